// Round 2
// baseline (762.699 us; speedup 1.0000x reference)
//
#include <hip/hip_runtime.h>
#include <hip/hip_bf16.h>
#include <math.h>

#define N_NODES 400000
#define DIM 256
#define NSEG 2048

typedef unsigned short u16;
typedef float floatx4 __attribute__((ext_vector_type(4)));
typedef __bf16 bf16x8 __attribute__((ext_vector_type(8)));

__device__ __forceinline__ u16 f2bf(float f) {
    __hip_bfloat16 h = __float2bfloat16(f);
    return *reinterpret_cast<u16*>(&h);
}
__device__ __forceinline__ float sigf(float x) { return 1.0f / (1.0f + __expf(-x)); }

// ---------------- segment starts from sorted index (int32/int64 auto-detect) ----------------
__global__ void seg_starts_kernel(const int* __restrict__ idx32, int* __restrict__ seg) {
    int n = blockIdx.x * blockDim.x + threadIdx.x;
    if (n >= N_NODES) return;
    // int64 little-endian: odd int32 slots are high words (=0 for values <2^31).
    // Last index is ~2047 (sorted, 400k draws over 2048) so idx32[N-1]!=0 iff int32.
    const bool is64 = (idx32[N_NODES - 1] == 0);
    int cur  = is64 ? idx32[2 * n] : idx32[n];
    int prev = (n == 0) ? -1 : (is64 ? idx32[2 * (n - 1)] : idx32[n - 1]);
    cur  = min(max(cur, -1), NSEG - 1);
    prev = min(max(prev, -1), NSEG - 1);
    for (int s = prev + 1; s <= cur; ++s) seg[s] = n;
    if (n == N_NODES - 1) {
        for (int s = cur + 1; s <= NSEG; ++s) seg[s] = N_NODES;
    }
}

// ---------------- weight prep: Wc = [Wih[:,0:256]+Whh | Wih[:,256:512]] (bf16), Wp -> bf16 ----
__global__ void prep_weights_kernel(const float* __restrict__ Wih, const float* __restrict__ Whh,
                                    const float* __restrict__ Wp,
                                    u16* __restrict__ Wc, u16* __restrict__ WpB) {
    int idx = blockIdx.x * blockDim.x + threadIdx.x;
    if (idx < 1024 * 512) {
        int j = idx >> 9, k = idx & 511;
        float v = Wih[(size_t)j * 512 + k];
        if (k < 256) v += Whh[(size_t)j * 256 + k];
        Wc[idx] = f2bf(v);
    }
    if (idx < 256 * 512) WpB[idx] = f2bf(Wp[idx]);
}

// ---------------- t=0 LSTM: all states zero -> gates = bih + bhh ----------------
__global__ void lstm_bias_kernel(const float* __restrict__ bih, const float* __restrict__ bhh,
                                 float* __restrict__ c, float* __restrict__ h,
                                 u16* __restrict__ A) {
    int idx = blockIdx.x * blockDim.x + threadIdx.x;   // NSEG*DIM
    if (idx >= NSEG * DIM) return;
    int b = idx >> 8, d = idx & 255;
    float gi = bih[d]       + bhh[d];
    float gg = bih[d + 512] + bhh[d + 512];
    float go = bih[d + 768] + bhh[d + 768];
    float cn = sigf(gi) * tanhf(gg);          // c_prev = 0: forget path vanishes
    float hn = sigf(go) * tanhf(cn);
    c[idx] = cn;
    h[idx] = hn;
    A[(size_t)b * 512 + d] = f2bf(hn);        // q part of q_star
}

// ---------------- LSTM pointwise from fp32 gates ----------------
__global__ void lstm_pw_kernel(const float* __restrict__ gates,
                               const float* __restrict__ bih, const float* __restrict__ bhh,
                               float* __restrict__ c, float* __restrict__ h,
                               u16* __restrict__ A) {
    int idx = blockIdx.x * blockDim.x + threadIdx.x;
    if (idx >= NSEG * DIM) return;
    int b = idx >> 8, d = idx & 255;
    const float* g = gates + (size_t)b * 1024;
    float gi = g[d]       + bih[d]       + bhh[d];
    float gf = g[d + 256] + bih[d + 256] + bhh[d + 256];
    float gg = g[d + 512] + bih[d + 512] + bhh[d + 512];
    float go = g[d + 768] + bih[d + 768] + bhh[d + 768];
    float cn = sigf(gf) * c[idx] + sigf(gi) * tanhf(gg);
    float hn = sigf(go) * tanhf(cn);
    c[idx] = cn;
    h[idx] = hn;
    A[(size_t)b * 512 + d] = f2bf(hn);
}

// ---------------- online-softmax segment attention: one block per segment ----------------
// r = softmax_seg(x . q) weighted sum of x; writes r (bf16) into A[:, 256:512]
__global__ __launch_bounds__(256) void attn_kernel(const float* __restrict__ x,
                                                   const int* __restrict__ seg,
                                                   const float* __restrict__ h,
                                                   u16* __restrict__ A) {
    const int b = blockIdx.x;
    const int tid = threadIdx.x;
    const int wave = tid >> 6, lane = tid & 63;
    int s0 = seg[b], s1 = seg[b + 1];
    s0 = max(s0, 0);
    s1 = min(s1, N_NODES);

    if (s1 <= s0) {            // empty segment: r = 0
        A[(size_t)b * 512 + 256 + tid] = (u16)0;
        return;
    }

    __shared__ float sm[4], sz[4];
    __shared__ float sr[4][256];

    // each lane owns dims 4*lane .. 4*lane+3 (full 256 dims per wave)
    const float4 qv = *(const float4*)(h + (size_t)b * 256 + lane * 4);

    float m = -INFINITY, z = 0.f;
    float r0 = 0.f, r1 = 0.f, r2 = 0.f, r3 = 0.f;

    for (int n = s0 + wave; n < s1; n += 4) {
        const float4 xv = *(const float4*)(x + (size_t)n * 256 + lane * 4);
        float e = xv.x * qv.x + xv.y * qv.y + xv.z * qv.z + xv.w * qv.w;
        e += __shfl_xor(e, 1);
        e += __shfl_xor(e, 2);
        e += __shfl_xor(e, 4);
        e += __shfl_xor(e, 8);
        e += __shfl_xor(e, 16);
        e += __shfl_xor(e, 32);
        float nm = fmaxf(m, e);
        float corr = __expf(m - nm);     // m=-inf first iter -> 0
        float p = __expf(e - nm);
        z = z * corr + p;
        r0 = r0 * corr + p * xv.x;
        r1 = r1 * corr + p * xv.y;
        r2 = r2 * corr + p * xv.z;
        r3 = r3 * corr + p * xv.w;
        m = nm;
    }

    if (lane == 0) { sm[wave] = m; sz[wave] = z; }
    sr[wave][lane * 4 + 0] = r0;
    sr[wave][lane * 4 + 1] = r1;
    sr[wave][lane * 4 + 2] = r2;
    sr[wave][lane * 4 + 3] = r3;
    __syncthreads();

    // merge 4 waves; thread t handles dim t
    float M = fmaxf(fmaxf(sm[0], sm[1]), fmaxf(sm[2], sm[3]));  // finite: wave0 saw node s0
    float zz = 0.f, rr = 0.f;
    for (int w = 0; w < 4; ++w) {
        float cw = __expf(sm[w] - M);    // empty wave: exp(-inf)=0
        zz += cw * sz[w];
        rr += cw * sr[w][tid];
    }
    A[(size_t)b * 512 + 256 + tid] = f2bf(rr / zz);
}

// ---------------- MFMA bf16 GEMM: C[M,N] = A[M,K] @ W[N,K]^T (+bias), fp32 out ----------
// 64x64 block tile, 4 waves in 2x2, each wave 32x32 via 2x2 mfma_f32_16x16x32_bf16
template<bool BIAS>
__global__ __launch_bounds__(256) void gemm_bt_kernel(const u16* __restrict__ Ag,
                                                      const u16* __restrict__ Wg,
                                                      const float* __restrict__ bias,
                                                      float* __restrict__ C,
                                                      int M, int N, int K) {
    __shared__ __align__(16) u16 As[64][40];   // +8 pad: 2-way LDS conflict only (free)
    __shared__ __align__(16) u16 Ws[64][40];

    const int tid = threadIdx.x;
    const int bm = blockIdx.x * 64;
    const int bn = blockIdx.y * 64;
    const int wave = tid >> 6, lane = tid & 63;
    const int wm = (wave & 1) * 32;
    const int wn = (wave >> 1) * 32;
    const int quad = lane >> 4;
    const int r16 = lane & 15;

    const int lrow = tid >> 2;         // 0..63
    const int lcol = (tid & 3) * 8;    // 0,8,16,24

    floatx4 acc[2][2] = {};

    for (int k0 = 0; k0 < K; k0 += 32) {
        *(uint4*)&As[lrow][lcol] = *(const uint4*)&Ag[(size_t)(bm + lrow) * K + k0 + lcol];
        *(uint4*)&Ws[lrow][lcol] = *(const uint4*)&Wg[(size_t)(bn + lrow) * K + k0 + lcol];
        __syncthreads();
        bf16x8 af0 = *(const bf16x8*)&As[wm + r16][quad * 8];
        bf16x8 af1 = *(const bf16x8*)&As[wm + 16 + r16][quad * 8];
        bf16x8 wf0 = *(const bf16x8*)&Ws[wn + r16][quad * 8];
        bf16x8 wf1 = *(const bf16x8*)&Ws[wn + 16 + r16][quad * 8];
        acc[0][0] = __builtin_amdgcn_mfma_f32_16x16x32_bf16(af0, wf0, acc[0][0], 0, 0, 0);
        acc[0][1] = __builtin_amdgcn_mfma_f32_16x16x32_bf16(af0, wf1, acc[0][1], 0, 0, 0);
        acc[1][0] = __builtin_amdgcn_mfma_f32_16x16x32_bf16(af1, wf0, acc[1][0], 0, 0, 0);
        acc[1][1] = __builtin_amdgcn_mfma_f32_16x16x32_bf16(af1, wf1, acc[1][1], 0, 0, 0);
        __syncthreads();
    }

    // C/D layout: col = lane&15, row = quad*4 + reg   [verified m89/m91]
    for (int tm = 0; tm < 2; ++tm)
        for (int tn = 0; tn < 2; ++tn)
            for (int j = 0; j < 4; ++j) {
                int row = bm + wm + tm * 16 + quad * 4 + j;
                int col = bn + wn + tn * 16 + r16;
                float v = acc[tm][tn][j];
                if (BIAS) v += bias[col];
                C[(size_t)row * N + col] = v;
            }
}

extern "C" void kernel_launch(void* const* d_in, const int* in_sizes, int n_in,
                              void* d_out, int out_size, void* d_ws, size_t ws_size,
                              hipStream_t stream) {
    const float* x   = (const float*)d_in[0];
    const int*   idx = (const int*)d_in[1];
    const float* Wih = (const float*)d_in[2];
    const float* Whh = (const float*)d_in[3];
    const float* bih = (const float*)d_in[4];
    const float* bhh = (const float*)d_in[5];
    const float* Wp  = (const float*)d_in[6];
    const float* bp  = (const float*)d_in[7];
    float* out = (float*)d_out;

    char* w = (char*)d_ws;
    int*   seg     = (int*)w;    w += 16384;                          // 8.2 KB used
    u16*   A       = (u16*)w;    w += (size_t)NSEG * 512 * 2;         // 2 MB  [h | r] bf16
    u16*   Wc      = (u16*)w;    w += (size_t)1024 * 512 * 2;         // 1 MB
    u16*   WpB     = (u16*)w;    w += (size_t)256 * 512 * 2;          // 256 KB
    float* h_f32   = (float*)w;  w += (size_t)NSEG * DIM * 4;         // 2 MB
    float* c_f32   = (float*)w;  w += (size_t)NSEG * DIM * 4;         // 2 MB
    float* gates   = (float*)w;  w += (size_t)NSEG * 1024 * 4;        // 8 MB

    seg_starts_kernel<<<(N_NODES + 255) / 256, 256, 0, stream>>>(idx, seg);
    prep_weights_kernel<<<(1024 * 512 + 255) / 256, 256, 0, stream>>>(Wih, Whh, Wp, Wc, WpB);

    // t = 0: states are zero -> bias-only LSTM
    lstm_bias_kernel<<<(NSEG * DIM + 255) / 256, 256, 0, stream>>>(bih, bhh, c_f32, h_f32, A);
    attn_kernel<<<NSEG, 256, 0, stream>>>(x, seg, h_f32, A);

    // t = 1, 2
    for (int t = 1; t < 3; ++t) {
        gemm_bt_kernel<false><<<dim3(2048 / 64, 1024 / 64), 256, 0, stream>>>(
            A, Wc, nullptr, gates, 2048, 1024, 512);
        lstm_pw_kernel<<<(NSEG * DIM + 255) / 256, 256, 0, stream>>>(gates, bih, bhh,
                                                                     c_f32, h_f32, A);
        attn_kernel<<<NSEG, 256, 0, stream>>>(x, seg, h_f32, A);
    }

    // out = q_star @ Wp^T + bp   (q_star == A)
    gemm_bt_kernel<true><<<dim3(2048 / 64, 256 / 64), 256, 0, stream>>>(
        A, WpB, bp, out, 2048, 256, 512);
}